// Round 13
// baseline (696.885 us; speedup 1.0000x reference)
//
#include <hip/hip_runtime.h>
#include <hip/hip_fp16.h>
#include <math.h>

// FrameletLayer: Chebyshev framelet graph conv + complex linear + CSiLU.
// Scaled recurrence That_k = T_k/32^k (fp16-safe); MFMA f16 for the complex GEMM.
// CSR via two-level bucket sort; 4B CSR entries {col:16|w:fp16} (N<=65536).
// SpMM steps write only T_k; Chebyshev weighted sum deferred to GEMM staging.
// SpMM: 2 chunk passes (256B half-rows), 32 lanes/row, 2 rows/wave, 4-wide
// pipelined gather (R8 structure, best measured). Rows individually sorted by
// DESCENDING degree (counting sort): wave pairs rows of ~equal degree (kills
// max(d1,d2) divergence), heavy rows first (no straggler tail). Linear
// [N][64-uint2] layout keeps every 256B half-row contiguous -> sorted pairing
// stays full-line on dst/prev. T4/T5 live inside d_out.

#define CH   128
#define NP   128   // half2 lanes per row (256 half)
#define NP4  64    // uint2 slots per row
#define RPB  128   // rows per bucket
#define MAXBUCK 512

typedef _Float16 half8 __attribute__((ext_vector_type(8)));
typedef float f32x4 __attribute__((ext_vector_type(4)));

__device__ __forceinline__ uint2 ntload_u2(const uint2* p) {
    unsigned long long v = __builtin_nontemporal_load((const unsigned long long*)p);
    uint2 r; r.x = (unsigned)v; r.y = (unsigned)(v >> 32);
    return r;
}

// ---------------- bucket-sort CSR build ----------------

__global__ __launch_bounds__(256) void bucket_hist_k(
        const int* __restrict__ row, int* __restrict__ bucket_cnt, int E, int nbuck) {
    __shared__ int h[MAXBUCK];
    for (int j = threadIdx.x; j < nbuck; j += 256) h[j] = 0;
    __syncthreads();
    int stride = gridDim.x * 256;
    for (int e = blockIdx.x * 256 + threadIdx.x; e < E; e += stride)
        atomicAdd(&h[row[e] >> 7], 1);
    __syncthreads();
    for (int j = threadIdx.x; j < nbuck; j += 256)
        if (h[j]) atomicAdd(&bucket_cnt[j], h[j]);
}

__global__ __launch_bounds__(512) void bucket_scan_k(
        const int* __restrict__ bucket_cnt, int* __restrict__ bucket_start,
        int* __restrict__ bucket_cursor, int nbuck, int E) {
    __shared__ int sd[MAXBUCK];
    int t = threadIdx.x;
    int v = (t < nbuck) ? bucket_cnt[t] : 0;
    sd[t] = v;
    __syncthreads();
    for (int off = 1; off < MAXBUCK; off <<= 1) {
        int y = (t >= off) ? sd[t - off] : 0;
        __syncthreads();
        sd[t] += y;
        __syncthreads();
    }
    int excl = sd[t] - v;
    if (t < nbuck) { bucket_start[t] = excl; bucket_cursor[t] = excl; }
    if (t == 0) bucket_start[nbuck] = E;
}

// tmp entry: {x = (row&127)<<16 | col, y = float_bits(w)}
__global__ __launch_bounds__(256) void bucket_place_k(
        const int* __restrict__ row, const int* __restrict__ col,
        const float* __restrict__ w, int* __restrict__ bucket_cursor,
        uint2* __restrict__ tmp, int E, int chunk, int nbuck) {
    __shared__ int cnt[MAXBUCK];
    __shared__ int cur[MAXBUCK];
    int e0 = blockIdx.x * chunk;
    int e1 = e0 + chunk; if (e1 > E) e1 = E;
    if (e0 >= E) return;
    for (int j = threadIdx.x; j < nbuck; j += 256) cnt[j] = 0;
    __syncthreads();
    for (int e = e0 + threadIdx.x; e < e1; e += 256)
        atomicAdd(&cnt[row[e] >> 7], 1);
    __syncthreads();
    for (int j = threadIdx.x; j < nbuck; j += 256) {
        int c = cnt[j];
        cur[j] = c ? atomicAdd(&bucket_cursor[j], c) : 0;
    }
    __syncthreads();
    for (int e = e0 + threadIdx.x; e < e1; e += 256) {
        int r = row[e];
        int b = r >> 7;
        int p = atomicAdd(&cur[b], 1);
        uint2 ent;
        ent.x = ((unsigned)(r & (RPB - 1)) << 16) | (unsigned)col[e];
        ent.y = __float_as_uint(w[e]);
        tmp[p] = ent;
    }
}

// one block per bucket: row hist + scan -> row_start; place 4B CSR entries
__global__ __launch_bounds__(256) void csr_build_k(
        const uint2* __restrict__ tmp, const int* __restrict__ bucket_start,
        int* __restrict__ row_start, unsigned* __restrict__ csr4,
        int N, int E, int nbuck) {
    __shared__ int hist[RPB];
    __shared__ int sc[RPB];
    __shared__ int curs[RPB];
    int b = blockIdx.x;
    int t = threadIdx.x;
    int base = bucket_start[b];
    int endp = bucket_start[b + 1];
    if (t < RPB) hist[t] = 0;
    __syncthreads();
    for (int e = base + t; e < endp; e += 256)
        atomicAdd(&hist[tmp[e].x >> 16], 1);
    __syncthreads();
    if (t < RPB) sc[t] = hist[t];
    __syncthreads();
    for (int off = 1; off < RPB; off <<= 1) {
        int y = 0;
        if (t < RPB && t >= off) y = sc[t - off];
        __syncthreads();
        if (t < RPB) sc[t] += y;
        __syncthreads();
    }
    int r0 = b << 7;
    if (t < RPB) {
        int excl = sc[t] - hist[t];
        if (r0 + t < N) row_start[r0 + t] = base + excl;
        curs[t] = base + excl;
    }
    if (b == nbuck - 1 && t == 0) row_start[N] = E;
    __syncthreads();
    for (int e = base + t; e < endp; e += 256) {
        uint2 ent = tmp[e];
        int rl = ent.x >> 16;
        unsigned c = ent.x & 0xffffu;
        float wv = __uint_as_float(ent.y) * (-1.0f / 16.0f);   // B/16 entries
        int p = atomicAdd(&curs[rl], 1);
        __half hw = __float2half(wv);
        csr4[p] = (c << 16) | (unsigned)__half_as_ushort(hw);
    }
}

// ---------------- individual-row descending degree counting sort ----------------

__device__ __forceinline__ int row_key(int d) {
    if (d > 255) d = 255;
    return 255 - d;   // descending degree
}

__global__ __launch_bounds__(256) void row_hist_k(
        const int* __restrict__ row_start, int* __restrict__ rh, int N) {
    __shared__ int h[256];
    h[threadIdx.x] = 0;
    __syncthreads();
    int stride = gridDim.x * 256;
    for (int i = blockIdx.x * 256 + threadIdx.x; i < N; i += stride)
        atomicAdd(&h[row_key(row_start[i + 1] - row_start[i])], 1);
    __syncthreads();
    if (h[threadIdx.x]) atomicAdd(&rh[threadIdx.x], h[threadIdx.x]);
}

__global__ __launch_bounds__(256) void row_scan_k(
        const int* __restrict__ rh, int* __restrict__ rcur) {
    __shared__ int sd[256];
    int t = threadIdx.x;
    int v = rh[t];
    sd[t] = v;
    __syncthreads();
    for (int off = 1; off < 256; off <<= 1) {
        int y = (t >= off) ? sd[t - off] : 0;
        __syncthreads();
        sd[t] += y;
        __syncthreads();
    }
    rcur[t] = sd[t] - v;
}

__global__ __launch_bounds__(256) void row_scatter_k(
        const int* __restrict__ row_start, int* __restrict__ rcur,
        int* __restrict__ sbeg, int* __restrict__ send, int* __restrict__ sorig,
        int N) {
    int i = blockIdx.x * 256 + threadIdx.x;
    if (i >= N) return;
    int a = row_start[i], b = row_start[i + 1];
    int q = atomicAdd(&rcur[row_key(b - a)], 1);
    sbeg[q] = a; send[q] = b; sorig[q] = i;
}

// cp[k] = (sum_f theta[f]*approx[f][k]) * 32^k
__global__ void coef_k(const float* __restrict__ approx, const float* __restrict__ theta,
                       float* cp) {
    int k = threadIdx.x;
    if (k < 6 && blockIdx.x == 0) {
        float s = 0.f;
        for (int f = 0; f < 4; f++) s += theta[f] * approx[f * 6 + k];
        float sc = 1.f;
        for (int j = 0; j < k; j++) sc *= 32.f;
        cp[k] = s * sc;
    }
}

// x (fp32 xr,xi) -> fused fp16 [N][128 half2]: p<64 real pair, p>=64 imag pair
__global__ void convert_x_k(const float2* __restrict__ xr2, const float2* __restrict__ xi2,
                            __half2* __restrict__ xbuf, int total) {
    int idx = blockIdx.x * blockDim.x + threadIdx.x;
    if (idx >= total) return;
    int i = idx >> 7;
    int p = idx & 127;
    float2 v = (p < 64) ? xr2[(size_t)i * 64 + p] : xi2[(size_t)i * 64 + (p - 64)];
    xbuf[idx] = __floats2half2_rn(v.x, v.y);
}

// WhT[j*256+k] = Wbig[k][j]; Wbig = [[Wr^T, Wi^T],[-Wi^T, Wr^T]] (k = input dim)
__global__ void build_whT_k(const float* __restrict__ Wr, const float* __restrict__ Wi,
                            _Float16* __restrict__ WhT) {
    int idx = blockIdx.x * 256 + threadIdx.x;
    int j = idx >> 8, k = idx & 255;
    float v;
    if (j < 128) {
        v = (k < 128) ? Wr[j * 128 + k] : -Wi[j * 128 + (k - 128)];
    } else {
        v = (k < 128) ? Wi[(j - 128) * 128 + k] : Wr[(j - 128) * 128 + (k - 128)];
    }
    WhT[idx] = (_Float16)v;
}

// ---------------- SpMM steps (chunked gather, 32 lanes/row, 2 rows/wave) ----

__device__ __forceinline__ void unpack4(uint2 v, float& a, float& b, float& c, float& d) {
    __half2 lo = *reinterpret_cast<__half2*>(&v.x);
    __half2 hi = *reinterpret_cast<__half2*>(&v.y);
    float2 f0 = __half22float2(lo);
    float2 f1 = __half22float2(hi);
    a = f0.x; b = f0.y; c = f1.x; d = f1.y;
}

__device__ __forceinline__ void decode(unsigned ent, int& c, float& wv) {
    c = (int)(ent >> 16);
    wv = __half2float(__ushort_as_half((unsigned short)(ent & 0xffffu)));
}

// s[0..3] += sum_e w_e * src[col_e][slot]; 4-edge groups, one group prefetched ahead
__device__ __forceinline__ void gather_row(
        const uint2* __restrict__ src, const unsigned* __restrict__ csr,
        int beg, int end, int slot,
        float& s0, float& s1, float& s2, float& s3) {
    int e = beg;
    unsigned c0, c1, c2, c3;
    if (e + 4 <= end) { c0 = csr[e]; c1 = csr[e+1]; c2 = csr[e+2]; c3 = csr[e+3]; }
    for (; e + 8 <= end; e += 4) {
        unsigned n0 = csr[e+4], n1 = csr[e+5], n2 = csr[e+6], n3 = csr[e+7];
        int ia, ib, ic, id; float wa, wb, wc, wd;
        decode(c0, ia, wa); decode(c1, ib, wb); decode(c2, ic, wc); decode(c3, id, wd);
        float a0,a1,a2,a3, b0,b1,b2,b3, d0,d1,d2,d3, f0,f1,f2,f3;
        unpack4(src[(size_t)ia * NP4 + slot], a0,a1,a2,a3);
        unpack4(src[(size_t)ib * NP4 + slot], b0,b1,b2,b3);
        unpack4(src[(size_t)ic * NP4 + slot], d0,d1,d2,d3);
        unpack4(src[(size_t)id * NP4 + slot], f0,f1,f2,f3);
        s0 += wa*a0 + wb*b0 + wc*d0 + wd*f0;
        s1 += wa*a1 + wb*b1 + wc*d1 + wd*f1;
        s2 += wa*a2 + wb*b2 + wc*d2 + wd*f2;
        s3 += wa*a3 + wb*b3 + wc*d3 + wd*f3;
        c0 = n0; c1 = n1; c2 = n2; c3 = n3;
    }
    if (e + 4 <= end) {
        int ia, ib, ic, id; float wa, wb, wc, wd;
        decode(c0, ia, wa); decode(c1, ib, wb); decode(c2, ic, wc); decode(c3, id, wd);
        float a0,a1,a2,a3, b0,b1,b2,b3, d0,d1,d2,d3, f0,f1,f2,f3;
        unpack4(src[(size_t)ia * NP4 + slot], a0,a1,a2,a3);
        unpack4(src[(size_t)ib * NP4 + slot], b0,b1,b2,b3);
        unpack4(src[(size_t)ic * NP4 + slot], d0,d1,d2,d3);
        unpack4(src[(size_t)id * NP4 + slot], f0,f1,f2,f3);
        s0 += wa*a0 + wb*b0 + wc*d0 + wd*f0;
        s1 += wa*a1 + wb*b1 + wc*d1 + wd*f1;
        s2 += wa*a2 + wb*b2 + wc*d2 + wd*f2;
        s3 += wa*a3 + wb*b3 + wc*d3 + wd*f3;
        e += 4;
    }
    for (; e < end; e++) {
        int ia; float wa;
        decode(csr[e], ia, wa);
        float a0,a1,a2,a3;
        unpack4(src[(size_t)ia * NP4 + slot], a0,a1,a2,a3);
        s0 += wa*a0; s1 += wa*a1; s2 += wa*a2; s3 += wa*a3;
    }
}

// That1 = (B/32) x -> dst only. Chunk pass: blockIdx&1 selects 256B half-row.
__global__ __launch_bounds__(256) void spmm_first4_k(
        const uint2* __restrict__ xb4,
        const int* __restrict__ sbeg, const int* __restrict__ send,
        const int* __restrict__ sorig, const unsigned* __restrict__ csr,
        uint2* __restrict__ dst, int N) {
    int blk = blockIdx.x;
    int c = blk & 1;
    int rb = blk >> 1;
    int t = threadIdx.x;
    int rl = t >> 5;            // 8 sorted rows per block, 2 per wave
    int p4 = t & 31;
    int p = rb * 8 + rl;
    if (p >= N) return;
    int slot = c * 32 + p4;
    int beg = sbeg[p], end = send[p];
    int i = sorig[p];
    float s0 = 0.f, s1 = 0.f, s2 = 0.f, s3 = 0.f;
    gather_row(xb4, csr, beg, end, slot, s0, s1, s2, s3);
    s0 *= 0.5f; s1 *= 0.5f; s2 *= 0.5f; s3 *= 0.5f;   // B/16 -> B/32
    uint2 pk;
    __half2 h0 = __floats2half2_rn(s0, s1);
    __half2 h1 = __floats2half2_rn(s2, s3);
    pk.x = *reinterpret_cast<unsigned*>(&h0);
    pk.y = *reinterpret_cast<unsigned*>(&h1);
    dst[(size_t)i * NP4 + slot] = pk;
}

// That_k = (B/16)*cur - prev/1024 -> dst only
__global__ __launch_bounds__(256) void spmm_step4_k(
        const uint2* __restrict__ cur, const uint2* __restrict__ prev,
        const int* __restrict__ sbeg, const int* __restrict__ send,
        const int* __restrict__ sorig, const unsigned* __restrict__ csr,
        uint2* __restrict__ dst, int N) {
    int blk = blockIdx.x;
    int c = blk & 1;
    int rb = blk >> 1;
    int t = threadIdx.x;
    int rl = t >> 5;
    int p4 = t & 31;
    int p = rb * 8 + rl;
    if (p >= N) return;
    int slot = c * 32 + p4;
    int beg = sbeg[p], end = send[p];
    int i = sorig[p];
    float s0 = 0.f, s1 = 0.f, s2 = 0.f, s3 = 0.f;
    gather_row(cur, csr, beg, end, slot, s0, s1, s2, s3);
    float p0,p1,p2,p3;
    unpack4(ntload_u2(&prev[(size_t)i * NP4 + slot]), p0,p1,p2,p3);
    const float inv = 1.0f / 1024.0f;
    float t0 = s0 - inv * p0;
    float t1v = s1 - inv * p1;
    float t2v = s2 - inv * p2;
    float t3v = s3 - inv * p3;
    uint2 pk;
    __half2 h0 = __floats2half2_rn(t0, t1v);
    __half2 h1 = __floats2half2_rn(t2v, t3v);
    pk.x = *reinterpret_cast<unsigned*>(&h0);
    pk.y = *reinterpret_cast<unsigned*>(&h1);
    dst[(size_t)i * NP4 + slot] = pk;
}

// ---------------- MFMA complex GEMM + SiLU ----------------
// Stage U = (sum_k cp[k]*That_k)/32 in f16 from 6 buffers (T4,T5 inside d_out,
// row-aligned with this block's output rows -> in-place safe), then MFMA.
__global__ __launch_bounds__(256) void gemm_silu_mfma_k(
        const _Float16* __restrict__ WhT,   // [j][k] = Wbig[k][j], 256x256
        const uint2* __restrict__ x0, const uint2* __restrict__ t1b,
        const uint2* __restrict__ t2b, const uint2* __restrict__ t3b,
        const float* __restrict__ cp,
        float* __restrict__ out, int N) {
    __shared__ _Float16 U[32][264];
    int t = threadIdx.x;
    int row0 = blockIdx.x * 32;
    const uint2* t4b = (const uint2*)out;                    // lower half: N*64 uint2
    const uint2* t5b = (const uint2*)out + (size_t)N * NP4;  // upper half
    const float isc = 1.0f / 32.0f;
    float w0 = cp[0], w1 = cp[1], w2 = cp[2], w3 = cp[3], w4 = cp[4], w5 = cp[5];
    for (int q = t; q < 2048; q += 256) {
        int r = q >> 6;
        int s = q & 63;
        int row = row0 + r;
        float a0 = 0.f, a1 = 0.f, a2 = 0.f, a3 = 0.f;
        if (row < N) {
            size_t idx = (size_t)row * NP4 + s;
            float v0,v1,v2,v3;
            unpack4(ntload_u2(&x0[idx]),  v0,v1,v2,v3);
            a0 += w0*v0; a1 += w0*v1; a2 += w0*v2; a3 += w0*v3;
            unpack4(ntload_u2(&t1b[idx]), v0,v1,v2,v3);
            a0 += w1*v0; a1 += w1*v1; a2 += w1*v2; a3 += w1*v3;
            unpack4(ntload_u2(&t2b[idx]), v0,v1,v2,v3);
            a0 += w2*v0; a1 += w2*v1; a2 += w2*v2; a3 += w2*v3;
            unpack4(ntload_u2(&t3b[idx]), v0,v1,v2,v3);
            a0 += w3*v0; a1 += w3*v1; a2 += w3*v2; a3 += w3*v3;
            unpack4(ntload_u2(&t4b[idx]), v0,v1,v2,v3);
            a0 += w4*v0; a1 += w4*v1; a2 += w4*v2; a3 += w4*v3;
            unpack4(ntload_u2(&t5b[idx]), v0,v1,v2,v3);
            a0 += w5*v0; a1 += w5*v1; a2 += w5*v2; a3 += w5*v3;
        }
        int k = s * 4;
        U[r][k]   = (_Float16)(a0 * isc);
        U[r][k+1] = (_Float16)(a1 * isc);
        U[r][k+2] = (_Float16)(a2 * isc);
        U[r][k+3] = (_Float16)(a3 * isc);
    }
    __syncthreads();

    int wave = t >> 6;
    int lane = t & 63;
    int colbase = wave * 64;
    int lr = lane & 15;
    int lg = lane >> 4;
    f32x4 acc[2][4] = {};
    for (int kb = 0; kb < 8; kb++) {
        int k0 = kb * 32 + lg * 8;
        half8 a0 = *(const half8*)&U[lr][k0];
        half8 a1 = *(const half8*)&U[16 + lr][k0];
        #pragma unroll
        for (int nf = 0; nf < 4; nf++) {
            int col = colbase + nf * 16 + lr;
            half8 b = *(const half8*)&WhT[(size_t)col * 256 + k0];
            acc[0][nf] = __builtin_amdgcn_mfma_f32_16x16x32_f16(a0, b, acc[0][nf], 0, 0, 0);
            acc[1][nf] = __builtin_amdgcn_mfma_f32_16x16x32_f16(a1, b, acc[1][nf], 0, 0, 0);
        }
    }

    #pragma unroll
    for (int mf = 0; mf < 2; mf++) {
        #pragma unroll
        for (int nf = 0; nf < 4; nf++) {
            int col = colbase + nf * 16 + lr;
            int half = col >> 7, jj = col & 127;
            #pragma unroll
            for (int r4 = 0; r4 < 4; r4++) {
                int row = row0 + mf * 16 + lg * 4 + r4;
                if (row < N) {
                    float v = acc[mf][nf][r4] * 32.f;
                    float sv = v / (1.f + expf(-v));
                    out[(size_t)half * N * CH + (size_t)row * CH + jj] = sv;
                }
            }
        }
    }
}

// ---------------- launch ----------------

extern "C" void kernel_launch(void* const* d_in, const int* in_sizes, int n_in,
                              void* d_out, int out_size, void* d_ws, size_t ws_size,
                              hipStream_t stream) {
    const float* xr     = (const float*)d_in[0];
    const float* xi     = (const float*)d_in[1];
    const int*   eidx   = (const int*)d_in[2];
    const float* ew     = (const float*)d_in[3];
    const float* approx = (const float*)d_in[4];
    const float* theta  = (const float*)d_in[5];
    const float* Wr     = (const float*)d_in[6];
    const float* Wi     = (const float*)d_in[7];

    const int N = in_sizes[0] / CH;
    const int E = in_sizes[3];
    const int* rowv = eidx;
    const int* colv = eidx + E;

    float* outp = (float*)d_out;

    char* w8 = (char*)d_ws;
    size_t off = 0;
    auto alloc = [&](size_t bytes) -> void* {
        void* ptr = w8 + off;
        off += (bytes + 255) & ~(size_t)255;
        return ptr;
    };
    float*    cp        = (float*)alloc(64 * 4);
    int*      bucket_cnt= (int*)alloc(MAXBUCK * 4);
    int*      bucket_st = (int*)alloc((MAXBUCK + 1) * 4);
    int*      bucket_cur= (int*)alloc(MAXBUCK * 4);
    int*      rh        = (int*)alloc(256 * 4);
    int*      rcur      = (int*)alloc(256 * 4);
    int*      row_start = (int*)alloc((size_t)(N + 1) * 4);
    int*      sbeg      = (int*)alloc((size_t)N * 4);
    int*      send      = (int*)alloc((size_t)N * 4);
    int*      sorig     = (int*)alloc((size_t)N * 4);
    unsigned* csr4      = (unsigned*)alloc((size_t)E * 4);
    _Float16* WhT       = (_Float16*)alloc(256 * 256 * 2);
    uint2*    xbuf      = (uint2*)alloc((size_t)N * NP4 * 8);
    uint2*    T1        = (uint2*)alloc((size_t)N * NP4 * 8);
    uint2*    T2        = (uint2*)alloc((size_t)N * NP4 * 8);
    uint2*    T3        = (uint2*)alloc((size_t)N * NP4 * 8);
    // tmp aliases T3's storage: tmp (E*8 = 12.8MB) is dead after csr_build_k,
    // T3 is first written in step 3 (long after). Stream-ordered safe.
    uint2*    tmp       = T3;
    // T4/T5 live inside d_out: each half is exactly N*NP4 uint2 (25.6 MB).
    uint2*    T4        = (uint2*)d_out;
    uint2*    T5        = (uint2*)d_out + (size_t)N * NP4;
    (void)ws_size;

    const int nbuck = (N + RPB - 1) / RPB;
    const int chunk = (E + 255) / 256;
    const int NH = N * NP;

    hipMemsetAsync(bucket_cnt, 0, (size_t)MAXBUCK * 4, stream);
    hipMemsetAsync(rh, 0, 256 * 4, stream);
    coef_k<<<1, 64, 0, stream>>>(approx, theta, cp);
    build_whT_k<<<256, 256, 0, stream>>>(Wr, Wi, WhT);
    bucket_hist_k<<<256, 256, 0, stream>>>(rowv, bucket_cnt, E, nbuck);
    bucket_scan_k<<<1, MAXBUCK, 0, stream>>>(bucket_cnt, bucket_st, bucket_cur, nbuck, E);
    bucket_place_k<<<256, 256, 0, stream>>>(rowv, colv, ew, bucket_cur, tmp, E, chunk, nbuck);
    csr_build_k<<<nbuck, 256, 0, stream>>>(tmp, bucket_st, row_start, csr4, N, E, nbuck);
    row_hist_k<<<128, 256, 0, stream>>>(row_start, rh, N);
    row_scan_k<<<1, 256, 0, stream>>>(rh, rcur);
    row_scatter_k<<<(N + 255) / 256, 256, 0, stream>>>(
        row_start, rcur, sbeg, send, sorig, N);
    convert_x_k<<<(NH + 255) / 256, 256, 0, stream>>>(
        (const float2*)xr, (const float2*)xi, (__half2*)xbuf, NH);

    // chunked SpMM: 8 sorted rows/block, 2 chunk passes -> grid = 2 * ceil(N/8)
    const int NG = 2 * ((N + 7) / 8);

    // T1 = (B/32) x
    spmm_first4_k<<<NG, 256, 0, stream>>>(xbuf, sbeg, send, sorig, csr4, T1, N);
    // T2 = (B/16) T1 - x/1024
    spmm_step4_k<<<NG, 256, 0, stream>>>(T1, xbuf, sbeg, send, sorig, csr4, T2, N);
    // T3 = (B/16) T2 - T1/1024
    spmm_step4_k<<<NG, 256, 0, stream>>>(T2, T1, sbeg, send, sorig, csr4, T3, N);
    // T4 = (B/16) T3 - T2/1024   (into d_out lower half)
    spmm_step4_k<<<NG, 256, 0, stream>>>(T3, T2, sbeg, send, sorig, csr4, T4, N);
    // T5 = (B/16) T4 - T3/1024   (into d_out upper half; gathers from d_out)
    spmm_step4_k<<<NG, 256, 0, stream>>>(T4, T3, sbeg, send, sorig, csr4, T5, N);

    gemm_silu_mfma_k<<<(N + 31) / 32, 256, 0, stream>>>(
        WhT, xbuf, T1, T2, T3, cp, outp, N);
}

// Round 14
// 627.365 us; speedup vs baseline: 1.1108x; 1.1108x over previous
//
#include <hip/hip_runtime.h>
#include <hip/hip_fp16.h>
#include <math.h>

// FrameletLayer: Chebyshev framelet graph conv + complex linear + CSiLU.
// Scaled recurrence That_k = T_k/32^k (fp16-safe); MFMA f16 for the complex GEMM.
// CSR via two-level bucket sort; 4B CSR entries {col:16|w:fp16} (N<=65536).
// Edges within each row are placed in COLUMN-BLOCK ascending order (col>>13):
// all SpMM blocks sweep col-phases in rough lockstep, so the per-phase gather
// working set (8192 rows x 256B = 2.1MB per chunk) stays L2-resident.
// SpMM: 2 chunk passes (256B half-rows), 32 lanes/row, 2 rows/wave, 4-wide
// pipelined gather (R8 structure). T4/T5 live inside d_out.

#define CH   128
#define NP   128   // half2 lanes per row (256 half)
#define NP4  64    // uint2 slots per row
#define RPB  128   // rows per bucket
#define MAXBUCK 512

typedef _Float16 half8 __attribute__((ext_vector_type(8)));
typedef float f32x4 __attribute__((ext_vector_type(4)));

__device__ __forceinline__ uint2 ntload_u2(const uint2* p) {
    unsigned long long v = __builtin_nontemporal_load((const unsigned long long*)p);
    uint2 r; r.x = (unsigned)v; r.y = (unsigned)(v >> 32);
    return r;
}

// ---------------- bucket-sort CSR build ----------------

__global__ __launch_bounds__(256) void bucket_hist_k(
        const int* __restrict__ row, int* __restrict__ bucket_cnt, int E, int nbuck) {
    __shared__ int h[MAXBUCK];
    for (int j = threadIdx.x; j < nbuck; j += 256) h[j] = 0;
    __syncthreads();
    int stride = gridDim.x * 256;
    for (int e = blockIdx.x * 256 + threadIdx.x; e < E; e += stride)
        atomicAdd(&h[row[e] >> 7], 1);
    __syncthreads();
    for (int j = threadIdx.x; j < nbuck; j += 256)
        if (h[j]) atomicAdd(&bucket_cnt[j], h[j]);
}

__global__ __launch_bounds__(512) void bucket_scan_k(
        const int* __restrict__ bucket_cnt, int* __restrict__ bucket_start,
        int* __restrict__ bucket_cursor, int nbuck, int E) {
    __shared__ int sd[MAXBUCK];
    int t = threadIdx.x;
    int v = (t < nbuck) ? bucket_cnt[t] : 0;
    sd[t] = v;
    __syncthreads();
    for (int off = 1; off < MAXBUCK; off <<= 1) {
        int y = (t >= off) ? sd[t - off] : 0;
        __syncthreads();
        sd[t] += y;
        __syncthreads();
    }
    int excl = sd[t] - v;
    if (t < nbuck) { bucket_start[t] = excl; bucket_cursor[t] = excl; }
    if (t == 0) bucket_start[nbuck] = E;
}

// tmp entry: {x = (row&127)<<16 | col, y = float_bits(w)}
__global__ __launch_bounds__(256) void bucket_place_k(
        const int* __restrict__ row, const int* __restrict__ col,
        const float* __restrict__ w, int* __restrict__ bucket_cursor,
        uint2* __restrict__ tmp, int E, int chunk, int nbuck) {
    __shared__ int cnt[MAXBUCK];
    __shared__ int cur[MAXBUCK];
    int e0 = blockIdx.x * chunk;
    int e1 = e0 + chunk; if (e1 > E) e1 = E;
    if (e0 >= E) return;
    for (int j = threadIdx.x; j < nbuck; j += 256) cnt[j] = 0;
    __syncthreads();
    for (int e = e0 + threadIdx.x; e < e1; e += 256)
        atomicAdd(&cnt[row[e] >> 7], 1);
    __syncthreads();
    for (int j = threadIdx.x; j < nbuck; j += 256) {
        int c = cnt[j];
        cur[j] = c ? atomicAdd(&bucket_cursor[j], c) : 0;
    }
    __syncthreads();
    for (int e = e0 + threadIdx.x; e < e1; e += 256) {
        int r = row[e];
        int b = r >> 7;
        int p = atomicAdd(&cur[b], 1);
        uint2 ent;
        ent.x = ((unsigned)(r & (RPB - 1)) << 16) | (unsigned)col[e];
        ent.y = __float_as_uint(w[e]);
        tmp[p] = ent;
    }
}

// one block per bucket: row hist + scan -> row_start; place 4B CSR entries in
// column-block ascending order (8 passes over the L2-resident bucket).
__global__ __launch_bounds__(256) void csr_build_k(
        const uint2* __restrict__ tmp, const int* __restrict__ bucket_start,
        int* __restrict__ row_start, unsigned* __restrict__ csr4,
        int N, int E, int nbuck) {
    __shared__ int hist[RPB];
    __shared__ int sc[RPB];
    __shared__ int curs[RPB];
    int b = blockIdx.x;
    int t = threadIdx.x;
    int base = bucket_start[b];
    int endp = bucket_start[b + 1];
    if (t < RPB) hist[t] = 0;
    __syncthreads();
    for (int e = base + t; e < endp; e += 256)
        atomicAdd(&hist[tmp[e].x >> 16], 1);
    __syncthreads();
    if (t < RPB) sc[t] = hist[t];
    __syncthreads();
    for (int off = 1; off < RPB; off <<= 1) {
        int y = 0;
        if (t < RPB && t >= off) y = sc[t - off];
        __syncthreads();
        if (t < RPB) sc[t] += y;
        __syncthreads();
    }
    int r0 = b << 7;
    if (t < RPB) {
        int excl = sc[t] - hist[t];
        if (r0 + t < N) row_start[r0 + t] = base + excl;
        curs[t] = base + excl;
    }
    if (b == nbuck - 1 && t == 0) row_start[N] = E;
    __syncthreads();
    // 8 passes: pass q places edges whose col-block (col>>13) == q.
    for (int q = 0; q < 8; q++) {
        for (int e = base + t; e < endp; e += 256) {
            uint2 ent = tmp[e];
            unsigned c = ent.x & 0xffffu;
            if ((int)(c >> 13) != q) continue;
            int rl = ent.x >> 16;
            float wv = __uint_as_float(ent.y) * (-1.0f / 16.0f);   // B/16 entries
            int p = atomicAdd(&curs[rl], 1);
            __half hw = __float2half(wv);
            csr4[p] = (c << 16) | (unsigned)__half_as_ushort(hw);
        }
        __syncthreads();
    }
}

// cp[k] = (sum_f theta[f]*approx[f][k]) * 32^k
__global__ void coef_k(const float* __restrict__ approx, const float* __restrict__ theta,
                       float* cp) {
    int k = threadIdx.x;
    if (k < 6 && blockIdx.x == 0) {
        float s = 0.f;
        for (int f = 0; f < 4; f++) s += theta[f] * approx[f * 6 + k];
        float sc = 1.f;
        for (int j = 0; j < k; j++) sc *= 32.f;
        cp[k] = s * sc;
    }
}

// x (fp32 xr,xi) -> fused fp16 [N][128 half2]: p<64 real pair, p>=64 imag pair
__global__ void convert_x_k(const float2* __restrict__ xr2, const float2* __restrict__ xi2,
                            __half2* __restrict__ xbuf, int total) {
    int idx = blockIdx.x * blockDim.x + threadIdx.x;
    if (idx >= total) return;
    int i = idx >> 7;
    int p = idx & 127;
    float2 v = (p < 64) ? xr2[(size_t)i * 64 + p] : xi2[(size_t)i * 64 + (p - 64)];
    xbuf[idx] = __floats2half2_rn(v.x, v.y);
}

// WhT[j*256+k] = Wbig[k][j]; Wbig = [[Wr^T, Wi^T],[-Wi^T, Wr^T]] (k = input dim)
__global__ void build_whT_k(const float* __restrict__ Wr, const float* __restrict__ Wi,
                            _Float16* __restrict__ WhT) {
    int idx = blockIdx.x * 256 + threadIdx.x;
    int j = idx >> 8, k = idx & 255;
    float v;
    if (j < 128) {
        v = (k < 128) ? Wr[j * 128 + k] : -Wi[j * 128 + (k - 128)];
    } else {
        v = (k < 128) ? Wi[(j - 128) * 128 + k] : Wr[(j - 128) * 128 + (k - 128)];
    }
    WhT[idx] = (_Float16)v;
}

// ---------------- SpMM steps (chunked half4 gather, 32 lanes/row, 2 rows/wave) ----

__device__ __forceinline__ void unpack4(uint2 v, float& a, float& b, float& c, float& d) {
    __half2 lo = *reinterpret_cast<__half2*>(&v.x);
    __half2 hi = *reinterpret_cast<__half2*>(&v.y);
    float2 f0 = __half22float2(lo);
    float2 f1 = __half22float2(hi);
    a = f0.x; b = f0.y; c = f1.x; d = f1.y;
}

__device__ __forceinline__ void decode(unsigned ent, int& c, float& wv) {
    c = (int)(ent >> 16);
    wv = __half2float(__ushort_as_half((unsigned short)(ent & 0xffffu)));
}

// s[0..3] += sum_e w_e * src[col_e][slot]; 4-edge groups, one group prefetched ahead
__device__ __forceinline__ void gather_row(
        const uint2* __restrict__ src, const unsigned* __restrict__ csr,
        int beg, int end, int slot,
        float& s0, float& s1, float& s2, float& s3) {
    int e = beg;
    unsigned c0, c1, c2, c3;
    if (e + 4 <= end) { c0 = csr[e]; c1 = csr[e+1]; c2 = csr[e+2]; c3 = csr[e+3]; }
    for (; e + 8 <= end; e += 4) {
        unsigned n0 = csr[e+4], n1 = csr[e+5], n2 = csr[e+6], n3 = csr[e+7];
        int ia, ib, ic, id; float wa, wb, wc, wd;
        decode(c0, ia, wa); decode(c1, ib, wb); decode(c2, ic, wc); decode(c3, id, wd);
        float a0,a1,a2,a3, b0,b1,b2,b3, d0,d1,d2,d3, f0,f1,f2,f3;
        unpack4(src[(size_t)ia * NP4 + slot], a0,a1,a2,a3);
        unpack4(src[(size_t)ib * NP4 + slot], b0,b1,b2,b3);
        unpack4(src[(size_t)ic * NP4 + slot], d0,d1,d2,d3);
        unpack4(src[(size_t)id * NP4 + slot], f0,f1,f2,f3);
        s0 += wa*a0 + wb*b0 + wc*d0 + wd*f0;
        s1 += wa*a1 + wb*b1 + wc*d1 + wd*f1;
        s2 += wa*a2 + wb*b2 + wc*d2 + wd*f2;
        s3 += wa*a3 + wb*b3 + wc*d3 + wd*f3;
        c0 = n0; c1 = n1; c2 = n2; c3 = n3;
    }
    if (e + 4 <= end) {
        int ia, ib, ic, id; float wa, wb, wc, wd;
        decode(c0, ia, wa); decode(c1, ib, wb); decode(c2, ic, wc); decode(c3, id, wd);
        float a0,a1,a2,a3, b0,b1,b2,b3, d0,d1,d2,d3, f0,f1,f2,f3;
        unpack4(src[(size_t)ia * NP4 + slot], a0,a1,a2,a3);
        unpack4(src[(size_t)ib * NP4 + slot], b0,b1,b2,b3);
        unpack4(src[(size_t)ic * NP4 + slot], d0,d1,d2,d3);
        unpack4(src[(size_t)id * NP4 + slot], f0,f1,f2,f3);
        s0 += wa*a0 + wb*b0 + wc*d0 + wd*f0;
        s1 += wa*a1 + wb*b1 + wc*d1 + wd*f1;
        s2 += wa*a2 + wb*b2 + wc*d2 + wd*f2;
        s3 += wa*a3 + wb*b3 + wc*d3 + wd*f3;
        e += 4;
    }
    for (; e < end; e++) {
        int ia; float wa;
        decode(csr[e], ia, wa);
        float a0,a1,a2,a3;
        unpack4(src[(size_t)ia * NP4 + slot], a0,a1,a2,a3);
        s0 += wa*a0; s1 += wa*a1; s2 += wa*a2; s3 += wa*a3;
    }
}

// That1 = (B/32) x -> dst only. Chunk pass: blockIdx&1 selects 256B half-row.
__global__ __launch_bounds__(256) void spmm_first4_k(
        const uint2* __restrict__ xb4,
        const int* __restrict__ row_start, const unsigned* __restrict__ csr,
        uint2* __restrict__ dst, int N) {
    int blk = blockIdx.x;
    int c = blk & 1;
    int rb = blk >> 1;
    int t = threadIdx.x;
    int rl = t >> 5;            // 8 rows per block, 2 per wave
    int p4 = t & 31;
    int i = rb * 8 + rl;
    if (i >= N) return;
    int slot = c * 32 + p4;
    int beg = row_start[i], end = row_start[i + 1];
    float s0 = 0.f, s1 = 0.f, s2 = 0.f, s3 = 0.f;
    gather_row(xb4, csr, beg, end, slot, s0, s1, s2, s3);
    s0 *= 0.5f; s1 *= 0.5f; s2 *= 0.5f; s3 *= 0.5f;   // B/16 -> B/32
    uint2 pk;
    __half2 h0 = __floats2half2_rn(s0, s1);
    __half2 h1 = __floats2half2_rn(s2, s3);
    pk.x = *reinterpret_cast<unsigned*>(&h0);
    pk.y = *reinterpret_cast<unsigned*>(&h1);
    dst[(size_t)i * NP4 + slot] = pk;
}

// That_k = (B/16)*cur - prev/1024 -> dst only
__global__ __launch_bounds__(256) void spmm_step4_k(
        const uint2* __restrict__ cur, const uint2* __restrict__ prev,
        const int* __restrict__ row_start, const unsigned* __restrict__ csr,
        uint2* __restrict__ dst, int N) {
    int blk = blockIdx.x;
    int c = blk & 1;
    int rb = blk >> 1;
    int t = threadIdx.x;
    int rl = t >> 5;
    int p4 = t & 31;
    int i = rb * 8 + rl;
    if (i >= N) return;
    int slot = c * 32 + p4;
    int beg = row_start[i], end = row_start[i + 1];
    float s0 = 0.f, s1 = 0.f, s2 = 0.f, s3 = 0.f;
    gather_row(cur, csr, beg, end, slot, s0, s1, s2, s3);
    float p0,p1,p2,p3;
    unpack4(ntload_u2(&prev[(size_t)i * NP4 + slot]), p0,p1,p2,p3);
    const float inv = 1.0f / 1024.0f;
    float t0 = s0 - inv * p0;
    float t1v = s1 - inv * p1;
    float t2v = s2 - inv * p2;
    float t3v = s3 - inv * p3;
    uint2 pk;
    __half2 h0 = __floats2half2_rn(t0, t1v);
    __half2 h1 = __floats2half2_rn(t2v, t3v);
    pk.x = *reinterpret_cast<unsigned*>(&h0);
    pk.y = *reinterpret_cast<unsigned*>(&h1);
    dst[(size_t)i * NP4 + slot] = pk;
}

// ---------------- MFMA complex GEMM + SiLU ----------------
// Stage U = (sum_k cp[k]*That_k)/32 in f16 from 6 buffers (T4,T5 inside d_out,
// row-aligned with this block's output rows -> in-place safe), then MFMA.
__global__ __launch_bounds__(256) void gemm_silu_mfma_k(
        const _Float16* __restrict__ WhT,   // [j][k] = Wbig[k][j], 256x256
        const uint2* __restrict__ x0, const uint2* __restrict__ t1b,
        const uint2* __restrict__ t2b, const uint2* __restrict__ t3b,
        const float* __restrict__ cp,
        float* __restrict__ out, int N) {
    __shared__ _Float16 U[32][264];
    int t = threadIdx.x;
    int row0 = blockIdx.x * 32;
    const uint2* t4b = (const uint2*)out;                    // lower half: N*64 uint2
    const uint2* t5b = (const uint2*)out + (size_t)N * NP4;  // upper half
    const float isc = 1.0f / 32.0f;
    float w0 = cp[0], w1 = cp[1], w2 = cp[2], w3 = cp[3], w4 = cp[4], w5 = cp[5];
    for (int q = t; q < 2048; q += 256) {
        int r = q >> 6;
        int s = q & 63;
        int row = row0 + r;
        float a0 = 0.f, a1 = 0.f, a2 = 0.f, a3 = 0.f;
        if (row < N) {
            size_t idx = (size_t)row * NP4 + s;
            float v0,v1,v2,v3;
            unpack4(ntload_u2(&x0[idx]),  v0,v1,v2,v3);
            a0 += w0*v0; a1 += w0*v1; a2 += w0*v2; a3 += w0*v3;
            unpack4(ntload_u2(&t1b[idx]), v0,v1,v2,v3);
            a0 += w1*v0; a1 += w1*v1; a2 += w1*v2; a3 += w1*v3;
            unpack4(ntload_u2(&t2b[idx]), v0,v1,v2,v3);
            a0 += w2*v0; a1 += w2*v1; a2 += w2*v2; a3 += w2*v3;
            unpack4(ntload_u2(&t3b[idx]), v0,v1,v2,v3);
            a0 += w3*v0; a1 += w3*v1; a2 += w3*v2; a3 += w3*v3;
            unpack4(ntload_u2(&t4b[idx]), v0,v1,v2,v3);
            a0 += w4*v0; a1 += w4*v1; a2 += w4*v2; a3 += w4*v3;
            unpack4(ntload_u2(&t5b[idx]), v0,v1,v2,v3);
            a0 += w5*v0; a1 += w5*v1; a2 += w5*v2; a3 += w5*v3;
        }
        int k = s * 4;
        U[r][k]   = (_Float16)(a0 * isc);
        U[r][k+1] = (_Float16)(a1 * isc);
        U[r][k+2] = (_Float16)(a2 * isc);
        U[r][k+3] = (_Float16)(a3 * isc);
    }
    __syncthreads();

    int wave = t >> 6;
    int lane = t & 63;
    int colbase = wave * 64;
    int lr = lane & 15;
    int lg = lane >> 4;
    f32x4 acc[2][4] = {};
    for (int kb = 0; kb < 8; kb++) {
        int k0 = kb * 32 + lg * 8;
        half8 a0 = *(const half8*)&U[lr][k0];
        half8 a1 = *(const half8*)&U[16 + lr][k0];
        #pragma unroll
        for (int nf = 0; nf < 4; nf++) {
            int col = colbase + nf * 16 + lr;
            half8 b = *(const half8*)&WhT[(size_t)col * 256 + k0];
            acc[0][nf] = __builtin_amdgcn_mfma_f32_16x16x32_f16(a0, b, acc[0][nf], 0, 0, 0);
            acc[1][nf] = __builtin_amdgcn_mfma_f32_16x16x32_f16(a1, b, acc[1][nf], 0, 0, 0);
        }
    }

    #pragma unroll
    for (int mf = 0; mf < 2; mf++) {
        #pragma unroll
        for (int nf = 0; nf < 4; nf++) {
            int col = colbase + nf * 16 + lr;
            int half = col >> 7, jj = col & 127;
            #pragma unroll
            for (int r4 = 0; r4 < 4; r4++) {
                int row = row0 + mf * 16 + lg * 4 + r4;
                if (row < N) {
                    float v = acc[mf][nf][r4] * 32.f;
                    float sv = v / (1.f + expf(-v));
                    out[(size_t)half * N * CH + (size_t)row * CH + jj] = sv;
                }
            }
        }
    }
}

// ---------------- launch ----------------

extern "C" void kernel_launch(void* const* d_in, const int* in_sizes, int n_in,
                              void* d_out, int out_size, void* d_ws, size_t ws_size,
                              hipStream_t stream) {
    const float* xr     = (const float*)d_in[0];
    const float* xi     = (const float*)d_in[1];
    const int*   eidx   = (const int*)d_in[2];
    const float* ew     = (const float*)d_in[3];
    const float* approx = (const float*)d_in[4];
    const float* theta  = (const float*)d_in[5];
    const float* Wr     = (const float*)d_in[6];
    const float* Wi     = (const float*)d_in[7];

    const int N = in_sizes[0] / CH;
    const int E = in_sizes[3];
    const int* rowv = eidx;
    const int* colv = eidx + E;

    float* outp = (float*)d_out;

    char* w8 = (char*)d_ws;
    size_t off = 0;
    auto alloc = [&](size_t bytes) -> void* {
        void* ptr = w8 + off;
        off += (bytes + 255) & ~(size_t)255;
        return ptr;
    };
    float*    cp        = (float*)alloc(64 * 4);
    int*      bucket_cnt= (int*)alloc(MAXBUCK * 4);
    int*      bucket_st = (int*)alloc((MAXBUCK + 1) * 4);
    int*      bucket_cur= (int*)alloc(MAXBUCK * 4);
    int*      row_start = (int*)alloc((size_t)(N + 1) * 4);
    unsigned* csr4      = (unsigned*)alloc((size_t)E * 4);
    _Float16* WhT       = (_Float16*)alloc(256 * 256 * 2);
    uint2*    xbuf      = (uint2*)alloc((size_t)N * NP4 * 8);
    uint2*    T1        = (uint2*)alloc((size_t)N * NP4 * 8);
    uint2*    T2        = (uint2*)alloc((size_t)N * NP4 * 8);
    uint2*    T3        = (uint2*)alloc((size_t)N * NP4 * 8);
    // tmp aliases T3's storage: tmp (E*8 = 12.8MB) is dead after csr_build_k,
    // T3 is first written in step 3 (long after). Stream-ordered safe.
    uint2*    tmp       = T3;
    // T4/T5 live inside d_out: each half is exactly N*NP4 uint2 (25.6 MB).
    uint2*    T4        = (uint2*)d_out;
    uint2*    T5        = (uint2*)d_out + (size_t)N * NP4;
    (void)ws_size;

    const int nbuck = (N + RPB - 1) / RPB;
    const int chunk = (E + 255) / 256;
    const int NH = N * NP;

    hipMemsetAsync(bucket_cnt, 0, (size_t)MAXBUCK * 4, stream);
    coef_k<<<1, 64, 0, stream>>>(approx, theta, cp);
    build_whT_k<<<256, 256, 0, stream>>>(Wr, Wi, WhT);
    bucket_hist_k<<<256, 256, 0, stream>>>(rowv, bucket_cnt, E, nbuck);
    bucket_scan_k<<<1, MAXBUCK, 0, stream>>>(bucket_cnt, bucket_st, bucket_cur, nbuck, E);
    bucket_place_k<<<256, 256, 0, stream>>>(rowv, colv, ew, bucket_cur, tmp, E, chunk, nbuck);
    csr_build_k<<<nbuck, 256, 0, stream>>>(tmp, bucket_st, row_start, csr4, N, E, nbuck);
    convert_x_k<<<(NH + 255) / 256, 256, 0, stream>>>(
        (const float2*)xr, (const float2*)xi, (__half2*)xbuf, NH);

    // chunked SpMM: 8 rows/block, 2 chunk passes -> grid = 2 * ceil(N/8)
    const int NG = 2 * ((N + 7) / 8);

    // T1 = (B/32) x
    spmm_first4_k<<<NG, 256, 0, stream>>>(xbuf, row_start, csr4, T1, N);
    // T2 = (B/16) T1 - x/1024
    spmm_step4_k<<<NG, 256, 0, stream>>>(T1, xbuf, row_start, csr4, T2, N);
    // T3 = (B/16) T2 - T1/1024
    spmm_step4_k<<<NG, 256, 0, stream>>>(T2, T1, row_start, csr4, T3, N);
    // T4 = (B/16) T3 - T2/1024   (into d_out lower half)
    spmm_step4_k<<<NG, 256, 0, stream>>>(T3, T2, row_start, csr4, T4, N);
    // T5 = (B/16) T4 - T3/1024   (into d_out upper half; gathers from d_out)
    spmm_step4_k<<<NG, 256, 0, stream>>>(T4, T3, row_start, csr4, T5, N);

    gemm_silu_mfma_k<<<(N + 31) / 32, 256, 0, stream>>>(
        WhT, xbuf, T1, T2, T3, cp, outp, N);
}

// Round 15
// 611.412 us; speedup vs baseline: 1.1398x; 1.0261x over previous
//
#include <hip/hip_runtime.h>
#include <hip/hip_fp16.h>
#include <math.h>

// FrameletLayer: Chebyshev framelet graph conv + complex linear + CSiLU.
// Scaled recurrence That_k = T_k/32^k (fp16-safe); MFMA f16 for the complex GEMM.
// CSR via two-level bucket sort; 4B CSR entries {col:16|w:fp16} (N<=65536).
// SpMM steps write only T_k; Chebyshev weighted sum deferred to GEMM staging.
// SpMM: 2 chunk passes (256B half-rows), 32 lanes/row, 2 rows/wave, 6-deep
// pipelined gather. chunk = blockIdx&1 (even/odd XCD parity). T4/T5 in d_out.

#define CH   128
#define NP   128   // half2 lanes per row (256 half)
#define NP4  64    // uint2 slots per row
#define RPB  128   // rows per bucket
#define MAXBUCK 512

typedef _Float16 half8 __attribute__((ext_vector_type(8)));
typedef float f32x4 __attribute__((ext_vector_type(4)));

__device__ __forceinline__ uint2 ntload_u2(const uint2* p) {
    unsigned long long v = __builtin_nontemporal_load((const unsigned long long*)p);
    uint2 r; r.x = (unsigned)v; r.y = (unsigned)(v >> 32);
    return r;
}

// ---------------- bucket-sort CSR build ----------------

__global__ __launch_bounds__(256) void bucket_hist_k(
        const int* __restrict__ row, int* __restrict__ bucket_cnt, int E, int nbuck) {
    __shared__ int h[MAXBUCK];
    for (int j = threadIdx.x; j < nbuck; j += 256) h[j] = 0;
    __syncthreads();
    int stride = gridDim.x * 256;
    for (int e = blockIdx.x * 256 + threadIdx.x; e < E; e += stride)
        atomicAdd(&h[row[e] >> 7], 1);
    __syncthreads();
    for (int j = threadIdx.x; j < nbuck; j += 256)
        if (h[j]) atomicAdd(&bucket_cnt[j], h[j]);
}

__global__ __launch_bounds__(512) void bucket_scan_k(
        const int* __restrict__ bucket_cnt, int* __restrict__ bucket_start,
        int* __restrict__ bucket_cursor, int nbuck, int E) {
    __shared__ int sd[MAXBUCK];
    int t = threadIdx.x;
    int v = (t < nbuck) ? bucket_cnt[t] : 0;
    sd[t] = v;
    __syncthreads();
    for (int off = 1; off < MAXBUCK; off <<= 1) {
        int y = (t >= off) ? sd[t - off] : 0;
        __syncthreads();
        sd[t] += y;
        __syncthreads();
    }
    int excl = sd[t] - v;
    if (t < nbuck) { bucket_start[t] = excl; bucket_cursor[t] = excl; }
    if (t == 0) bucket_start[nbuck] = E;
}

// tmp entry: {x = (row&127)<<16 | col, y = float_bits(w)}
__global__ __launch_bounds__(256) void bucket_place_k(
        const int* __restrict__ row, const int* __restrict__ col,
        const float* __restrict__ w, int* __restrict__ bucket_cursor,
        uint2* __restrict__ tmp, int E, int chunk, int nbuck) {
    __shared__ int cnt[MAXBUCK];
    __shared__ int cur[MAXBUCK];
    int e0 = blockIdx.x * chunk;
    int e1 = e0 + chunk; if (e1 > E) e1 = E;
    if (e0 >= E) return;
    for (int j = threadIdx.x; j < nbuck; j += 256) cnt[j] = 0;
    __syncthreads();
    for (int e = e0 + threadIdx.x; e < e1; e += 256)
        atomicAdd(&cnt[row[e] >> 7], 1);
    __syncthreads();
    for (int j = threadIdx.x; j < nbuck; j += 256) {
        int c = cnt[j];
        cur[j] = c ? atomicAdd(&bucket_cursor[j], c) : 0;
    }
    __syncthreads();
    for (int e = e0 + threadIdx.x; e < e1; e += 256) {
        int r = row[e];
        int b = r >> 7;
        int p = atomicAdd(&cur[b], 1);
        uint2 ent;
        ent.x = ((unsigned)(r & (RPB - 1)) << 16) | (unsigned)col[e];
        ent.y = __float_as_uint(w[e]);
        tmp[p] = ent;
    }
}

// one block per bucket: row hist + scan -> row_start; place 4B CSR entries
__global__ __launch_bounds__(256) void csr_build_k(
        const uint2* __restrict__ tmp, const int* __restrict__ bucket_start,
        int* __restrict__ row_start, unsigned* __restrict__ csr4,
        int N, int E, int nbuck) {
    __shared__ int hist[RPB];
    __shared__ int sc[RPB];
    __shared__ int curs[RPB];
    int b = blockIdx.x;
    int t = threadIdx.x;
    int base = bucket_start[b];
    int endp = bucket_start[b + 1];
    if (t < RPB) hist[t] = 0;
    __syncthreads();
    for (int e = base + t; e < endp; e += 256)
        atomicAdd(&hist[tmp[e].x >> 16], 1);
    __syncthreads();
    if (t < RPB) sc[t] = hist[t];
    __syncthreads();
    for (int off = 1; off < RPB; off <<= 1) {
        int y = 0;
        if (t < RPB && t >= off) y = sc[t - off];
        __syncthreads();
        if (t < RPB) sc[t] += y;
        __syncthreads();
    }
    int r0 = b << 7;
    if (t < RPB) {
        int excl = sc[t] - hist[t];
        if (r0 + t < N) row_start[r0 + t] = base + excl;
        curs[t] = base + excl;
    }
    if (b == nbuck - 1 && t == 0) row_start[N] = E;
    __syncthreads();
    for (int e = base + t; e < endp; e += 256) {
        uint2 ent = tmp[e];
        int rl = ent.x >> 16;
        unsigned c = ent.x & 0xffffu;
        float wv = __uint_as_float(ent.y) * (-1.0f / 16.0f);   // B/16 entries
        int p = atomicAdd(&curs[rl], 1);
        __half hw = __float2half(wv);
        csr4[p] = (c << 16) | (unsigned)__half_as_ushort(hw);
    }
}

// cp[k] = (sum_f theta[f]*approx[f][k]) * 32^k
__global__ void coef_k(const float* __restrict__ approx, const float* __restrict__ theta,
                       float* cp) {
    int k = threadIdx.x;
    if (k < 6 && blockIdx.x == 0) {
        float s = 0.f;
        for (int f = 0; f < 4; f++) s += theta[f] * approx[f * 6 + k];
        float sc = 1.f;
        for (int j = 0; j < k; j++) sc *= 32.f;
        cp[k] = s * sc;
    }
}

// x (fp32 xr,xi) -> fused fp16 [N][128 half2]: p<64 real pair, p>=64 imag pair
__global__ void convert_x_k(const float2* __restrict__ xr2, const float2* __restrict__ xi2,
                            __half2* __restrict__ xbuf, int total) {
    int idx = blockIdx.x * blockDim.x + threadIdx.x;
    if (idx >= total) return;
    int i = idx >> 7;
    int p = idx & 127;
    float2 v = (p < 64) ? xr2[(size_t)i * 64 + p] : xi2[(size_t)i * 64 + (p - 64)];
    xbuf[idx] = __floats2half2_rn(v.x, v.y);
}

// WhT[j*256+k] = Wbig[k][j]; Wbig = [[Wr^T, Wi^T],[-Wi^T, Wr^T]] (k = input dim)
__global__ void build_whT_k(const float* __restrict__ Wr, const float* __restrict__ Wi,
                            _Float16* __restrict__ WhT) {
    int idx = blockIdx.x * 256 + threadIdx.x;
    int j = idx >> 8, k = idx & 255;
    float v;
    if (j < 128) {
        v = (k < 128) ? Wr[j * 128 + k] : -Wi[j * 128 + (k - 128)];
    } else {
        v = (k < 128) ? Wi[(j - 128) * 128 + k] : Wr[(j - 128) * 128 + (k - 128)];
    }
    WhT[idx] = (_Float16)v;
}

// ---------------- SpMM steps (chunked half4 gather, 32 lanes/row, 2 rows/wave) ----

__device__ __forceinline__ void unpack4(uint2 v, float& a, float& b, float& c, float& d) {
    __half2 lo = *reinterpret_cast<__half2*>(&v.x);
    __half2 hi = *reinterpret_cast<__half2*>(&v.y);
    float2 f0 = __half22float2(lo);
    float2 f1 = __half22float2(hi);
    a = f0.x; b = f0.y; c = f1.x; d = f1.y;
}

__device__ __forceinline__ void decode(unsigned ent, int& c, float& wv) {
    c = (int)(ent >> 16);
    wv = __half2float(__ushort_as_half((unsigned short)(ent & 0xffffu)));
}

#define GF1(ENT)                                                               \
    {                                                                          \
        int ia; float wa;                                                      \
        decode(ENT, ia, wa);                                                   \
        float a0,a1,a2,a3;                                                     \
        unpack4(src[(size_t)ia * NP4 + slot], a0,a1,a2,a3);                    \
        s0 += wa*a0; s1 += wa*a1; s2 += wa*a2; s3 += wa*a3;                    \
    }

// s[0..3] += sum_e w_e * src[col_e][slot]; 6-edge groups, one group prefetched ahead
__device__ __forceinline__ void gather_row(
        const uint2* __restrict__ src, const unsigned* __restrict__ csr,
        int beg, int end, int slot,
        float& s0, float& s1, float& s2, float& s3) {
    int e = beg;
    unsigned c0, c1, c2, c3, c4, c5;
    if (e + 6 <= end) {
        c0 = csr[e]; c1 = csr[e+1]; c2 = csr[e+2];
        c3 = csr[e+3]; c4 = csr[e+4]; c5 = csr[e+5];
    }
    for (; e + 12 <= end; e += 6) {
        unsigned n0 = csr[e+6], n1 = csr[e+7], n2 = csr[e+8];
        unsigned n3 = csr[e+9], n4 = csr[e+10], n5 = csr[e+11];
        GF1(c0); GF1(c1); GF1(c2); GF1(c3); GF1(c4); GF1(c5);
        c0 = n0; c1 = n1; c2 = n2; c3 = n3; c4 = n4; c5 = n5;
    }
    if (e + 6 <= end) {
        GF1(c0); GF1(c1); GF1(c2); GF1(c3); GF1(c4); GF1(c5);
        e += 6;
    }
    for (; e < end; e++) { unsigned ent = csr[e]; GF1(ent); }
}

// That1 = (B/32) x -> dst only. Chunk pass: blockIdx&1 selects 256B half-row.
__global__ __launch_bounds__(256) void spmm_first4_k(
        const uint2* __restrict__ xb4,
        const int* __restrict__ row_start, const unsigned* __restrict__ csr,
        uint2* __restrict__ dst, int N) {
    int blk = blockIdx.x;
    int c = blk & 1;
    int rb = blk >> 1;
    int t = threadIdx.x;
    int rl = t >> 5;            // 8 rows per block, 2 per wave
    int p4 = t & 31;
    int i = rb * 8 + rl;
    if (i >= N) return;
    int slot = c * 32 + p4;
    int beg = row_start[i], end = row_start[i + 1];
    float s0 = 0.f, s1 = 0.f, s2 = 0.f, s3 = 0.f;
    gather_row(xb4, csr, beg, end, slot, s0, s1, s2, s3);
    s0 *= 0.5f; s1 *= 0.5f; s2 *= 0.5f; s3 *= 0.5f;   // B/16 -> B/32
    uint2 pk;
    __half2 h0 = __floats2half2_rn(s0, s1);
    __half2 h1 = __floats2half2_rn(s2, s3);
    pk.x = *reinterpret_cast<unsigned*>(&h0);
    pk.y = *reinterpret_cast<unsigned*>(&h1);
    dst[(size_t)i * NP4 + slot] = pk;
}

// That_k = (B/16)*cur - prev/1024 -> dst only
__global__ __launch_bounds__(256) void spmm_step4_k(
        const uint2* __restrict__ cur, const uint2* __restrict__ prev,
        const int* __restrict__ row_start, const unsigned* __restrict__ csr,
        uint2* __restrict__ dst, int N) {
    int blk = blockIdx.x;
    int c = blk & 1;
    int rb = blk >> 1;
    int t = threadIdx.x;
    int rl = t >> 5;
    int p4 = t & 31;
    int i = rb * 8 + rl;
    if (i >= N) return;
    int slot = c * 32 + p4;
    int beg = row_start[i], end = row_start[i + 1];
    float s0 = 0.f, s1 = 0.f, s2 = 0.f, s3 = 0.f;
    gather_row(cur, csr, beg, end, slot, s0, s1, s2, s3);
    float p0,p1,p2,p3;
    unpack4(ntload_u2(&prev[(size_t)i * NP4 + slot]), p0,p1,p2,p3);
    const float inv = 1.0f / 1024.0f;
    float t0 = s0 - inv * p0;
    float t1v = s1 - inv * p1;
    float t2v = s2 - inv * p2;
    float t3v = s3 - inv * p3;
    uint2 pk;
    __half2 h0 = __floats2half2_rn(t0, t1v);
    __half2 h1 = __floats2half2_rn(t2v, t3v);
    pk.x = *reinterpret_cast<unsigned*>(&h0);
    pk.y = *reinterpret_cast<unsigned*>(&h1);
    dst[(size_t)i * NP4 + slot] = pk;
}

// ---------------- MFMA complex GEMM + SiLU ----------------
// Stage U = (sum_k cp[k]*That_k)/32 in f16 from 6 buffers (T4,T5 inside d_out,
// row-aligned with this block's output rows -> in-place safe), then MFMA.
__global__ __launch_bounds__(256) void gemm_silu_mfma_k(
        const _Float16* __restrict__ WhT,   // [j][k] = Wbig[k][j], 256x256
        const uint2* __restrict__ x0, const uint2* __restrict__ t1b,
        const uint2* __restrict__ t2b, const uint2* __restrict__ t3b,
        const float* __restrict__ cp,
        float* __restrict__ out, int N) {
    __shared__ _Float16 U[32][264];
    int t = threadIdx.x;
    int row0 = blockIdx.x * 32;
    const uint2* t4b = (const uint2*)out;                    // lower half: N*64 uint2
    const uint2* t5b = (const uint2*)out + (size_t)N * NP4;  // upper half
    const float isc = 1.0f / 32.0f;
    float w0 = cp[0], w1 = cp[1], w2 = cp[2], w3 = cp[3], w4 = cp[4], w5 = cp[5];
    for (int q = t; q < 2048; q += 256) {
        int r = q >> 6;
        int s = q & 63;
        int row = row0 + r;
        float a0 = 0.f, a1 = 0.f, a2 = 0.f, a3 = 0.f;
        if (row < N) {
            size_t idx = (size_t)row * NP4 + s;
            float v0,v1,v2,v3;
            unpack4(ntload_u2(&x0[idx]),  v0,v1,v2,v3);
            a0 += w0*v0; a1 += w0*v1; a2 += w0*v2; a3 += w0*v3;
            unpack4(ntload_u2(&t1b[idx]), v0,v1,v2,v3);
            a0 += w1*v0; a1 += w1*v1; a2 += w1*v2; a3 += w1*v3;
            unpack4(ntload_u2(&t2b[idx]), v0,v1,v2,v3);
            a0 += w2*v0; a1 += w2*v1; a2 += w2*v2; a3 += w2*v3;
            unpack4(ntload_u2(&t3b[idx]), v0,v1,v2,v3);
            a0 += w3*v0; a1 += w3*v1; a2 += w3*v2; a3 += w3*v3;
            unpack4(ntload_u2(&t4b[idx]), v0,v1,v2,v3);
            a0 += w4*v0; a1 += w4*v1; a2 += w4*v2; a3 += w4*v3;
            unpack4(ntload_u2(&t5b[idx]), v0,v1,v2,v3);
            a0 += w5*v0; a1 += w5*v1; a2 += w5*v2; a3 += w5*v3;
        }
        int k = s * 4;
        U[r][k]   = (_Float16)(a0 * isc);
        U[r][k+1] = (_Float16)(a1 * isc);
        U[r][k+2] = (_Float16)(a2 * isc);
        U[r][k+3] = (_Float16)(a3 * isc);
    }
    __syncthreads();

    int wave = t >> 6;
    int lane = t & 63;
    int colbase = wave * 64;
    int lr = lane & 15;
    int lg = lane >> 4;
    f32x4 acc[2][4] = {};
    for (int kb = 0; kb < 8; kb++) {
        int k0 = kb * 32 + lg * 8;
        half8 a0 = *(const half8*)&U[lr][k0];
        half8 a1 = *(const half8*)&U[16 + lr][k0];
        #pragma unroll
        for (int nf = 0; nf < 4; nf++) {
            int col = colbase + nf * 16 + lr;
            half8 b = *(const half8*)&WhT[(size_t)col * 256 + k0];
            acc[0][nf] = __builtin_amdgcn_mfma_f32_16x16x32_f16(a0, b, acc[0][nf], 0, 0, 0);
            acc[1][nf] = __builtin_amdgcn_mfma_f32_16x16x32_f16(a1, b, acc[1][nf], 0, 0, 0);
        }
    }

    #pragma unroll
    for (int mf = 0; mf < 2; mf++) {
        #pragma unroll
        for (int nf = 0; nf < 4; nf++) {
            int col = colbase + nf * 16 + lr;
            int half = col >> 7, jj = col & 127;
            #pragma unroll
            for (int r4 = 0; r4 < 4; r4++) {
                int row = row0 + mf * 16 + lg * 4 + r4;
                if (row < N) {
                    float v = acc[mf][nf][r4] * 32.f;
                    float sv = v / (1.f + expf(-v));
                    out[(size_t)half * N * CH + (size_t)row * CH + jj] = sv;
                }
            }
        }
    }
}

// ---------------- launch ----------------

extern "C" void kernel_launch(void* const* d_in, const int* in_sizes, int n_in,
                              void* d_out, int out_size, void* d_ws, size_t ws_size,
                              hipStream_t stream) {
    const float* xr     = (const float*)d_in[0];
    const float* xi     = (const float*)d_in[1];
    const int*   eidx   = (const int*)d_in[2];
    const float* ew     = (const float*)d_in[3];
    const float* approx = (const float*)d_in[4];
    const float* theta  = (const float*)d_in[5];
    const float* Wr     = (const float*)d_in[6];
    const float* Wi     = (const float*)d_in[7];

    const int N = in_sizes[0] / CH;
    const int E = in_sizes[3];
    const int* rowv = eidx;
    const int* colv = eidx + E;

    float* outp = (float*)d_out;

    char* w8 = (char*)d_ws;
    size_t off = 0;
    auto alloc = [&](size_t bytes) -> void* {
        void* ptr = w8 + off;
        off += (bytes + 255) & ~(size_t)255;
        return ptr;
    };
    float*    cp        = (float*)alloc(64 * 4);
    int*      bucket_cnt= (int*)alloc(MAXBUCK * 4);
    int*      bucket_st = (int*)alloc((MAXBUCK + 1) * 4);
    int*      bucket_cur= (int*)alloc(MAXBUCK * 4);
    int*      row_start = (int*)alloc((size_t)(N + 1) * 4);
    unsigned* csr4      = (unsigned*)alloc((size_t)E * 4);
    _Float16* WhT       = (_Float16*)alloc(256 * 256 * 2);
    uint2*    xbuf      = (uint2*)alloc((size_t)N * NP4 * 8);
    uint2*    T1        = (uint2*)alloc((size_t)N * NP4 * 8);
    uint2*    T2        = (uint2*)alloc((size_t)N * NP4 * 8);
    uint2*    T3        = (uint2*)alloc((size_t)N * NP4 * 8);
    // tmp aliases T3's storage: tmp (E*8 = 12.8MB) is dead after csr_build_k,
    // T3 is first written in step 3 (long after). Stream-ordered safe.
    uint2*    tmp       = T3;
    // T4/T5 live inside d_out: each half is exactly N*NP4 uint2 (25.6 MB).
    uint2*    T4        = (uint2*)d_out;
    uint2*    T5        = (uint2*)d_out + (size_t)N * NP4;
    (void)ws_size;

    const int nbuck = (N + RPB - 1) / RPB;
    const int chunk = (E + 255) / 256;
    const int NH = N * NP;

    hipMemsetAsync(bucket_cnt, 0, (size_t)MAXBUCK * 4, stream);
    coef_k<<<1, 64, 0, stream>>>(approx, theta, cp);
    build_whT_k<<<256, 256, 0, stream>>>(Wr, Wi, WhT);
    bucket_hist_k<<<256, 256, 0, stream>>>(rowv, bucket_cnt, E, nbuck);
    bucket_scan_k<<<1, MAXBUCK, 0, stream>>>(bucket_cnt, bucket_st, bucket_cur, nbuck, E);
    bucket_place_k<<<256, 256, 0, stream>>>(rowv, colv, ew, bucket_cur, tmp, E, chunk, nbuck);
    csr_build_k<<<nbuck, 256, 0, stream>>>(tmp, bucket_st, row_start, csr4, N, E, nbuck);
    convert_x_k<<<(NH + 255) / 256, 256, 0, stream>>>(
        (const float2*)xr, (const float2*)xi, (__half2*)xbuf, NH);

    // chunked SpMM: 8 rows/block, 2 chunk passes -> grid = 2 * ceil(N/8)
    const int NG = 2 * ((N + 7) / 8);

    // T1 = (B/32) x
    spmm_first4_k<<<NG, 256, 0, stream>>>(xbuf, row_start, csr4, T1, N);
    // T2 = (B/16) T1 - x/1024
    spmm_step4_k<<<NG, 256, 0, stream>>>(T1, xbuf, row_start, csr4, T2, N);
    // T3 = (B/16) T2 - T1/1024
    spmm_step4_k<<<NG, 256, 0, stream>>>(T2, T1, row_start, csr4, T3, N);
    // T4 = (B/16) T3 - T2/1024   (into d_out lower half)
    spmm_step4_k<<<NG, 256, 0, stream>>>(T3, T2, row_start, csr4, T4, N);
    // T5 = (B/16) T4 - T3/1024   (into d_out upper half; gathers from d_out)
    spmm_step4_k<<<NG, 256, 0, stream>>>(T4, T3, row_start, csr4, T5, N);

    gemm_silu_mfma_k<<<(N + 31) / 32, 256, 0, stream>>>(
        WhT, xbuf, T1, T2, T3, cp, outp, N);
}

// Round 16
// 602.625 us; speedup vs baseline: 1.1564x; 1.0146x over previous
//
#include <hip/hip_runtime.h>
#include <hip/hip_fp16.h>
#include <math.h>

// FrameletLayer: Chebyshev framelet graph conv + complex linear + CSiLU.
// Scaled recurrence That_k = T_k/32^k (fp16-safe); MFMA f16 for the complex GEMM.
// CSR via two-level bucket sort; 4B CSR entries {col:16|w:fp16} (N<=65536).
// SpMM steps write only T_k; Chebyshev weighted sum deferred to GEMM staging.
// SpMM runs as 2 chunk passes (256B half-rows): 32 lanes/row, 2 rows/wave,
// 4-deep pipelined gather; chunk = blockIdx&1 (even/odd XCD parity).
// T4/T5 live inside d_out. [R8 configuration — best measured: 604 us]

#define CH   128
#define NP   128   // half2 lanes per row (256 half)
#define NP4  64    // uint2 slots per row
#define RPB  128   // rows per bucket
#define MAXBUCK 512

typedef _Float16 half8 __attribute__((ext_vector_type(8)));
typedef float f32x4 __attribute__((ext_vector_type(4)));

__device__ __forceinline__ uint2 ntload_u2(const uint2* p) {
    unsigned long long v = __builtin_nontemporal_load((const unsigned long long*)p);
    uint2 r; r.x = (unsigned)v; r.y = (unsigned)(v >> 32);
    return r;
}

// ---------------- bucket-sort CSR build ----------------

__global__ __launch_bounds__(256) void bucket_hist_k(
        const int* __restrict__ row, int* __restrict__ bucket_cnt, int E, int nbuck) {
    __shared__ int h[MAXBUCK];
    for (int j = threadIdx.x; j < nbuck; j += 256) h[j] = 0;
    __syncthreads();
    int stride = gridDim.x * 256;
    for (int e = blockIdx.x * 256 + threadIdx.x; e < E; e += stride)
        atomicAdd(&h[row[e] >> 7], 1);
    __syncthreads();
    for (int j = threadIdx.x; j < nbuck; j += 256)
        if (h[j]) atomicAdd(&bucket_cnt[j], h[j]);
}

__global__ __launch_bounds__(512) void bucket_scan_k(
        const int* __restrict__ bucket_cnt, int* __restrict__ bucket_start,
        int* __restrict__ bucket_cursor, int nbuck, int E) {
    __shared__ int sd[MAXBUCK];
    int t = threadIdx.x;
    int v = (t < nbuck) ? bucket_cnt[t] : 0;
    sd[t] = v;
    __syncthreads();
    for (int off = 1; off < MAXBUCK; off <<= 1) {
        int y = (t >= off) ? sd[t - off] : 0;
        __syncthreads();
        sd[t] += y;
        __syncthreads();
    }
    int excl = sd[t] - v;
    if (t < nbuck) { bucket_start[t] = excl; bucket_cursor[t] = excl; }
    if (t == 0) bucket_start[nbuck] = E;
}

// tmp entry: {x = (row&127)<<16 | col, y = float_bits(w)}
__global__ __launch_bounds__(256) void bucket_place_k(
        const int* __restrict__ row, const int* __restrict__ col,
        const float* __restrict__ w, int* __restrict__ bucket_cursor,
        uint2* __restrict__ tmp, int E, int chunk, int nbuck) {
    __shared__ int cnt[MAXBUCK];
    __shared__ int cur[MAXBUCK];
    int e0 = blockIdx.x * chunk;
    int e1 = e0 + chunk; if (e1 > E) e1 = E;
    if (e0 >= E) return;
    for (int j = threadIdx.x; j < nbuck; j += 256) cnt[j] = 0;
    __syncthreads();
    for (int e = e0 + threadIdx.x; e < e1; e += 256)
        atomicAdd(&cnt[row[e] >> 7], 1);
    __syncthreads();
    for (int j = threadIdx.x; j < nbuck; j += 256) {
        int c = cnt[j];
        cur[j] = c ? atomicAdd(&bucket_cursor[j], c) : 0;
    }
    __syncthreads();
    for (int e = e0 + threadIdx.x; e < e1; e += 256) {
        int r = row[e];
        int b = r >> 7;
        int p = atomicAdd(&cur[b], 1);
        uint2 ent;
        ent.x = ((unsigned)(r & (RPB - 1)) << 16) | (unsigned)col[e];
        ent.y = __float_as_uint(w[e]);
        tmp[p] = ent;
    }
}

// one block per bucket: row hist + scan -> row_start; place 4B CSR entries
__global__ __launch_bounds__(256) void csr_build_k(
        const uint2* __restrict__ tmp, const int* __restrict__ bucket_start,
        int* __restrict__ row_start, unsigned* __restrict__ csr4,
        int N, int E, int nbuck) {
    __shared__ int hist[RPB];
    __shared__ int sc[RPB];
    __shared__ int curs[RPB];
    int b = blockIdx.x;
    int t = threadIdx.x;
    int base = bucket_start[b];
    int endp = bucket_start[b + 1];
    if (t < RPB) hist[t] = 0;
    __syncthreads();
    for (int e = base + t; e < endp; e += 256)
        atomicAdd(&hist[tmp[e].x >> 16], 1);
    __syncthreads();
    if (t < RPB) sc[t] = hist[t];
    __syncthreads();
    for (int off = 1; off < RPB; off <<= 1) {
        int y = 0;
        if (t < RPB && t >= off) y = sc[t - off];
        __syncthreads();
        if (t < RPB) sc[t] += y;
        __syncthreads();
    }
    int r0 = b << 7;
    if (t < RPB) {
        int excl = sc[t] - hist[t];
        if (r0 + t < N) row_start[r0 + t] = base + excl;
        curs[t] = base + excl;
    }
    if (b == nbuck - 1 && t == 0) row_start[N] = E;
    __syncthreads();
    for (int e = base + t; e < endp; e += 256) {
        uint2 ent = tmp[e];
        int rl = ent.x >> 16;
        unsigned c = ent.x & 0xffffu;
        float wv = __uint_as_float(ent.y) * (-1.0f / 16.0f);   // B/16 entries
        int p = atomicAdd(&curs[rl], 1);
        __half hw = __float2half(wv);
        csr4[p] = (c << 16) | (unsigned)__half_as_ushort(hw);
    }
}

// cp[k] = (sum_f theta[f]*approx[f][k]) * 32^k
__global__ void coef_k(const float* __restrict__ approx, const float* __restrict__ theta,
                       float* cp) {
    int k = threadIdx.x;
    if (k < 6 && blockIdx.x == 0) {
        float s = 0.f;
        for (int f = 0; f < 4; f++) s += theta[f] * approx[f * 6 + k];
        float sc = 1.f;
        for (int j = 0; j < k; j++) sc *= 32.f;
        cp[k] = s * sc;
    }
}

// x (fp32 xr,xi) -> fused fp16 [N][128 half2]: p<64 real pair, p>=64 imag pair
__global__ void convert_x_k(const float2* __restrict__ xr2, const float2* __restrict__ xi2,
                            __half2* __restrict__ xbuf, int total) {
    int idx = blockIdx.x * blockDim.x + threadIdx.x;
    if (idx >= total) return;
    int i = idx >> 7;
    int p = idx & 127;
    float2 v = (p < 64) ? xr2[(size_t)i * 64 + p] : xi2[(size_t)i * 64 + (p - 64)];
    xbuf[idx] = __floats2half2_rn(v.x, v.y);
}

// WhT[j*256+k] = Wbig[k][j]; Wbig = [[Wr^T, Wi^T],[-Wi^T, Wr^T]] (k = input dim)
__global__ void build_whT_k(const float* __restrict__ Wr, const float* __restrict__ Wi,
                            _Float16* __restrict__ WhT) {
    int idx = blockIdx.x * 256 + threadIdx.x;
    int j = idx >> 8, k = idx & 255;
    float v;
    if (j < 128) {
        v = (k < 128) ? Wr[j * 128 + k] : -Wi[j * 128 + (k - 128)];
    } else {
        v = (k < 128) ? Wi[(j - 128) * 128 + k] : Wr[(j - 128) * 128 + (k - 128)];
    }
    WhT[idx] = (_Float16)v;
}

// ---------------- SpMM steps (chunked half4 gather, 32 lanes/row, 2 rows/wave) ----

__device__ __forceinline__ void unpack4(uint2 v, float& a, float& b, float& c, float& d) {
    __half2 lo = *reinterpret_cast<__half2*>(&v.x);
    __half2 hi = *reinterpret_cast<__half2*>(&v.y);
    float2 f0 = __half22float2(lo);
    float2 f1 = __half22float2(hi);
    a = f0.x; b = f0.y; c = f1.x; d = f1.y;
}

__device__ __forceinline__ void decode(unsigned ent, int& c, float& wv) {
    c = (int)(ent >> 16);
    wv = __half2float(__ushort_as_half((unsigned short)(ent & 0xffffu)));
}

// s[0..3] += sum_e w_e * src[col_e][slot]; 4-edge groups, one group prefetched ahead
__device__ __forceinline__ void gather_row(
        const uint2* __restrict__ src, const unsigned* __restrict__ csr,
        int beg, int end, int slot,
        float& s0, float& s1, float& s2, float& s3) {
    int e = beg;
    unsigned c0, c1, c2, c3;
    if (e + 4 <= end) { c0 = csr[e]; c1 = csr[e+1]; c2 = csr[e+2]; c3 = csr[e+3]; }
    for (; e + 8 <= end; e += 4) {
        unsigned n0 = csr[e+4], n1 = csr[e+5], n2 = csr[e+6], n3 = csr[e+7];
        int ia, ib, ic, id; float wa, wb, wc, wd;
        decode(c0, ia, wa); decode(c1, ib, wb); decode(c2, ic, wc); decode(c3, id, wd);
        float a0,a1,a2,a3, b0,b1,b2,b3, d0,d1,d2,d3, f0,f1,f2,f3;
        unpack4(src[(size_t)ia * NP4 + slot], a0,a1,a2,a3);
        unpack4(src[(size_t)ib * NP4 + slot], b0,b1,b2,b3);
        unpack4(src[(size_t)ic * NP4 + slot], d0,d1,d2,d3);
        unpack4(src[(size_t)id * NP4 + slot], f0,f1,f2,f3);
        s0 += wa*a0 + wb*b0 + wc*d0 + wd*f0;
        s1 += wa*a1 + wb*b1 + wc*d1 + wd*f1;
        s2 += wa*a2 + wb*b2 + wc*d2 + wd*f2;
        s3 += wa*a3 + wb*b3 + wc*d3 + wd*f3;
        c0 = n0; c1 = n1; c2 = n2; c3 = n3;
    }
    if (e + 4 <= end) {
        int ia, ib, ic, id; float wa, wb, wc, wd;
        decode(c0, ia, wa); decode(c1, ib, wb); decode(c2, ic, wc); decode(c3, id, wd);
        float a0,a1,a2,a3, b0,b1,b2,b3, d0,d1,d2,d3, f0,f1,f2,f3;
        unpack4(src[(size_t)ia * NP4 + slot], a0,a1,a2,a3);
        unpack4(src[(size_t)ib * NP4 + slot], b0,b1,b2,b3);
        unpack4(src[(size_t)ic * NP4 + slot], d0,d1,d2,d3);
        unpack4(src[(size_t)id * NP4 + slot], f0,f1,f2,f3);
        s0 += wa*a0 + wb*b0 + wc*d0 + wd*f0;
        s1 += wa*a1 + wb*b1 + wc*d1 + wd*f1;
        s2 += wa*a2 + wb*b2 + wc*d2 + wd*f2;
        s3 += wa*a3 + wb*b3 + wc*d3 + wd*f3;
        e += 4;
    }
    for (; e < end; e++) {
        int ia; float wa;
        decode(csr[e], ia, wa);
        float a0,a1,a2,a3;
        unpack4(src[(size_t)ia * NP4 + slot], a0,a1,a2,a3);
        s0 += wa*a0; s1 += wa*a1; s2 += wa*a2; s3 += wa*a3;
    }
}

// That1 = (B/32) x -> dst only. Chunk pass: blockIdx&1 selects 256B half-row.
__global__ __launch_bounds__(256) void spmm_first4_k(
        const uint2* __restrict__ xb4,
        const int* __restrict__ row_start, const unsigned* __restrict__ csr,
        uint2* __restrict__ dst, int N) {
    int blk = blockIdx.x;
    int c = blk & 1;
    int rb = blk >> 1;
    int t = threadIdx.x;
    int rl = t >> 5;            // 8 rows per block, 2 per wave
    int p4 = t & 31;
    int i = rb * 8 + rl;
    if (i >= N) return;
    int slot = c * 32 + p4;
    int beg = row_start[i], end = row_start[i + 1];
    float s0 = 0.f, s1 = 0.f, s2 = 0.f, s3 = 0.f;
    gather_row(xb4, csr, beg, end, slot, s0, s1, s2, s3);
    s0 *= 0.5f; s1 *= 0.5f; s2 *= 0.5f; s3 *= 0.5f;   // B/16 -> B/32
    uint2 pk;
    __half2 h0 = __floats2half2_rn(s0, s1);
    __half2 h1 = __floats2half2_rn(s2, s3);
    pk.x = *reinterpret_cast<unsigned*>(&h0);
    pk.y = *reinterpret_cast<unsigned*>(&h1);
    dst[(size_t)i * NP4 + slot] = pk;
}

// That_k = (B/16)*cur - prev/1024 -> dst only
__global__ __launch_bounds__(256) void spmm_step4_k(
        const uint2* __restrict__ cur, const uint2* __restrict__ prev,
        const int* __restrict__ row_start, const unsigned* __restrict__ csr,
        uint2* __restrict__ dst, int N) {
    int blk = blockIdx.x;
    int c = blk & 1;
    int rb = blk >> 1;
    int t = threadIdx.x;
    int rl = t >> 5;
    int p4 = t & 31;
    int i = rb * 8 + rl;
    if (i >= N) return;
    int slot = c * 32 + p4;
    int beg = row_start[i], end = row_start[i + 1];
    float s0 = 0.f, s1 = 0.f, s2 = 0.f, s3 = 0.f;
    gather_row(cur, csr, beg, end, slot, s0, s1, s2, s3);
    float p0,p1,p2,p3;
    unpack4(ntload_u2(&prev[(size_t)i * NP4 + slot]), p0,p1,p2,p3);
    const float inv = 1.0f / 1024.0f;
    float t0 = s0 - inv * p0;
    float t1v = s1 - inv * p1;
    float t2v = s2 - inv * p2;
    float t3v = s3 - inv * p3;
    uint2 pk;
    __half2 h0 = __floats2half2_rn(t0, t1v);
    __half2 h1 = __floats2half2_rn(t2v, t3v);
    pk.x = *reinterpret_cast<unsigned*>(&h0);
    pk.y = *reinterpret_cast<unsigned*>(&h1);
    dst[(size_t)i * NP4 + slot] = pk;
}

// ---------------- MFMA complex GEMM + SiLU ----------------
// Stage U = (sum_k cp[k]*That_k)/32 in f16 from 6 buffers (T4,T5 inside d_out,
// row-aligned with this block's output rows -> in-place safe), then MFMA.
__global__ __launch_bounds__(256) void gemm_silu_mfma_k(
        const _Float16* __restrict__ WhT,   // [j][k] = Wbig[k][j], 256x256
        const uint2* __restrict__ x0, const uint2* __restrict__ t1b,
        const uint2* __restrict__ t2b, const uint2* __restrict__ t3b,
        const float* __restrict__ cp,
        float* __restrict__ out, int N) {
    __shared__ _Float16 U[32][264];
    int t = threadIdx.x;
    int row0 = blockIdx.x * 32;
    const uint2* t4b = (const uint2*)out;                    // lower half: N*64 uint2
    const uint2* t5b = (const uint2*)out + (size_t)N * NP4;  // upper half
    const float isc = 1.0f / 32.0f;
    float w0 = cp[0], w1 = cp[1], w2 = cp[2], w3 = cp[3], w4 = cp[4], w5 = cp[5];
    for (int q = t; q < 2048; q += 256) {
        int r = q >> 6;
        int s = q & 63;
        int row = row0 + r;
        float a0 = 0.f, a1 = 0.f, a2 = 0.f, a3 = 0.f;
        if (row < N) {
            size_t idx = (size_t)row * NP4 + s;
            float v0,v1,v2,v3;
            unpack4(ntload_u2(&x0[idx]),  v0,v1,v2,v3);
            a0 += w0*v0; a1 += w0*v1; a2 += w0*v2; a3 += w0*v3;
            unpack4(ntload_u2(&t1b[idx]), v0,v1,v2,v3);
            a0 += w1*v0; a1 += w1*v1; a2 += w1*v2; a3 += w1*v3;
            unpack4(ntload_u2(&t2b[idx]), v0,v1,v2,v3);
            a0 += w2*v0; a1 += w2*v1; a2 += w2*v2; a3 += w2*v3;
            unpack4(ntload_u2(&t3b[idx]), v0,v1,v2,v3);
            a0 += w3*v0; a1 += w3*v1; a2 += w3*v2; a3 += w3*v3;
            unpack4(ntload_u2(&t4b[idx]), v0,v1,v2,v3);
            a0 += w4*v0; a1 += w4*v1; a2 += w4*v2; a3 += w4*v3;
            unpack4(ntload_u2(&t5b[idx]), v0,v1,v2,v3);
            a0 += w5*v0; a1 += w5*v1; a2 += w5*v2; a3 += w5*v3;
        }
        int k = s * 4;
        U[r][k]   = (_Float16)(a0 * isc);
        U[r][k+1] = (_Float16)(a1 * isc);
        U[r][k+2] = (_Float16)(a2 * isc);
        U[r][k+3] = (_Float16)(a3 * isc);
    }
    __syncthreads();

    int wave = t >> 6;
    int lane = t & 63;
    int colbase = wave * 64;
    int lr = lane & 15;
    int lg = lane >> 4;
    f32x4 acc[2][4] = {};
    for (int kb = 0; kb < 8; kb++) {
        int k0 = kb * 32 + lg * 8;
        half8 a0 = *(const half8*)&U[lr][k0];
        half8 a1 = *(const half8*)&U[16 + lr][k0];
        #pragma unroll
        for (int nf = 0; nf < 4; nf++) {
            int col = colbase + nf * 16 + lr;
            half8 b = *(const half8*)&WhT[(size_t)col * 256 + k0];
            acc[0][nf] = __builtin_amdgcn_mfma_f32_16x16x32_f16(a0, b, acc[0][nf], 0, 0, 0);
            acc[1][nf] = __builtin_amdgcn_mfma_f32_16x16x32_f16(a1, b, acc[1][nf], 0, 0, 0);
        }
    }

    #pragma unroll
    for (int mf = 0; mf < 2; mf++) {
        #pragma unroll
        for (int nf = 0; nf < 4; nf++) {
            int col = colbase + nf * 16 + lr;
            int half = col >> 7, jj = col & 127;
            #pragma unroll
            for (int r4 = 0; r4 < 4; r4++) {
                int row = row0 + mf * 16 + lg * 4 + r4;
                if (row < N) {
                    float v = acc[mf][nf][r4] * 32.f;
                    float sv = v / (1.f + expf(-v));
                    out[(size_t)half * N * CH + (size_t)row * CH + jj] = sv;
                }
            }
        }
    }
}

// ---------------- launch ----------------

extern "C" void kernel_launch(void* const* d_in, const int* in_sizes, int n_in,
                              void* d_out, int out_size, void* d_ws, size_t ws_size,
                              hipStream_t stream) {
    const float* xr     = (const float*)d_in[0];
    const float* xi     = (const float*)d_in[1];
    const int*   eidx   = (const int*)d_in[2];
    const float* ew     = (const float*)d_in[3];
    const float* approx = (const float*)d_in[4];
    const float* theta  = (const float*)d_in[5];
    const float* Wr     = (const float*)d_in[6];
    const float* Wi     = (const float*)d_in[7];

    const int N = in_sizes[0] / CH;
    const int E = in_sizes[3];
    const int* rowv = eidx;
    const int* colv = eidx + E;

    float* outp = (float*)d_out;

    char* w8 = (char*)d_ws;
    size_t off = 0;
    auto alloc = [&](size_t bytes) -> void* {
        void* ptr = w8 + off;
        off += (bytes + 255) & ~(size_t)255;
        return ptr;
    };
    float*    cp        = (float*)alloc(64 * 4);
    int*      bucket_cnt= (int*)alloc(MAXBUCK * 4);
    int*      bucket_st = (int*)alloc((MAXBUCK + 1) * 4);
    int*      bucket_cur= (int*)alloc(MAXBUCK * 4);
    int*      row_start = (int*)alloc((size_t)(N + 1) * 4);
    unsigned* csr4      = (unsigned*)alloc((size_t)E * 4);
    _Float16* WhT       = (_Float16*)alloc(256 * 256 * 2);
    uint2*    xbuf      = (uint2*)alloc((size_t)N * NP4 * 8);
    uint2*    T1        = (uint2*)alloc((size_t)N * NP4 * 8);
    uint2*    T2        = (uint2*)alloc((size_t)N * NP4 * 8);
    uint2*    T3        = (uint2*)alloc((size_t)N * NP4 * 8);
    // tmp aliases T3's storage: tmp (E*8 = 12.8MB) is dead after csr_build_k,
    // T3 is first written in step 3 (long after). Stream-ordered safe.
    uint2*    tmp       = T3;
    // T4/T5 live inside d_out: each half is exactly N*NP4 uint2 (25.6 MB).
    uint2*    T4        = (uint2*)d_out;
    uint2*    T5        = (uint2*)d_out + (size_t)N * NP4;
    (void)ws_size;

    const int nbuck = (N + RPB - 1) / RPB;
    const int chunk = (E + 255) / 256;
    const int NH = N * NP;

    hipMemsetAsync(bucket_cnt, 0, (size_t)MAXBUCK * 4, stream);
    coef_k<<<1, 64, 0, stream>>>(approx, theta, cp);
    build_whT_k<<<256, 256, 0, stream>>>(Wr, Wi, WhT);
    bucket_hist_k<<<256, 256, 0, stream>>>(rowv, bucket_cnt, E, nbuck);
    bucket_scan_k<<<1, MAXBUCK, 0, stream>>>(bucket_cnt, bucket_st, bucket_cur, nbuck, E);
    bucket_place_k<<<256, 256, 0, stream>>>(rowv, colv, ew, bucket_cur, tmp, E, chunk, nbuck);
    csr_build_k<<<nbuck, 256, 0, stream>>>(tmp, bucket_st, row_start, csr4, N, E, nbuck);
    convert_x_k<<<(NH + 255) / 256, 256, 0, stream>>>(
        (const float2*)xr, (const float2*)xi, (__half2*)xbuf, NH);

    // chunked SpMM: 8 rows/block, 2 chunk passes -> grid = 2 * ceil(N/8)
    const int NG = 2 * ((N + 7) / 8);

    // T1 = (B/32) x
    spmm_first4_k<<<NG, 256, 0, stream>>>(xbuf, row_start, csr4, T1, N);
    // T2 = (B/16) T1 - x/1024
    spmm_step4_k<<<NG, 256, 0, stream>>>(T1, xbuf, row_start, csr4, T2, N);
    // T3 = (B/16) T2 - T1/1024
    spmm_step4_k<<<NG, 256, 0, stream>>>(T2, T1, row_start, csr4, T3, N);
    // T4 = (B/16) T3 - T2/1024   (into d_out lower half)
    spmm_step4_k<<<NG, 256, 0, stream>>>(T3, T2, row_start, csr4, T4, N);
    // T5 = (B/16) T4 - T3/1024   (into d_out upper half; gathers from d_out)
    spmm_step4_k<<<NG, 256, 0, stream>>>(T4, T3, row_start, csr4, T5, N);

    gemm_silu_mfma_k<<<(N + 31) / 32, 256, 0, stream>>>(
        WhT, xbuf, T1, T2, T3, cp, outp, N);
}